// Round 1
// baseline (483.223 us; speedup 1.0000x reference)
//
#include <hip/hip_runtime.h>

#define N_TOK 16384
#define DDIM  2048
#define KC    8

__device__ __forceinline__ float wave_sum(float v){
  #pragma unroll
  for (int off = 32; off > 0; off >>= 1)
    v += __shfl_xor(v, off, 64);
  return v;
}

__device__ __forceinline__ float gelu_tanh(float v){
  const float c = 0.7978845608028654f;
  float tt = c * v * (1.0f + 0.044715f * v * v);
  float e  = __expf(2.0f * tt);
  float th = 1.0f - 2.0f / (e + 1.0f);
  return 0.5f * v * (1.0f + th);
}

// ---------------------------------------------------------------------------
// Pass A: per-token argmax assignment + per-block segment partial sums.
// Block = 256 threads; thread t owns d = {4t..4t+3} and {1024+4t..1024+4t+3}.
// Prototypes (raw) held in 64 VGPRs/thread; segment sums in 64 acc VGPRs.
// ---------------------------------------------------------------------------
__global__ __launch_bounds__(256, 2)
void k_assign(const float* __restrict__ x, const float* __restrict__ proto,
              float* __restrict__ psums, float* __restrict__ pcnts, int ntok)
{
  const int t = threadIdx.x;
  const int wave = t >> 6, lane = t & 63;
  const int d0 = 4*t, d1 = DDIM/2 + 4*t;

  __shared__ float red[4*KC];
  __shared__ float sInv[KC];
  __shared__ float sCnt[KC];
  __shared__ int   sA;

  float4 P0[KC], P1[KC];
  float4 acc0[KC], acc1[KC];
  #pragma unroll
  for (int k = 0; k < KC; ++k){
    P0[k] = *(const float4*)(proto + k*DDIM + d0);
    P1[k] = *(const float4*)(proto + k*DDIM + d1);
    acc0[k] = make_float4(0.f,0.f,0.f,0.f);
    acc1[k] = make_float4(0.f,0.f,0.f,0.f);
  }
  if (t < KC) sCnt[t] = 0.f;

  // 1/||P_k|| (eps 1e-12, matches _normalize default) — argmax of dot*invP
  // equals argmax of clipped cosine sims (positive scale, monotone clip).
  #pragma unroll
  for (int k = 0; k < KC; ++k){
    float ss = P0[k].x*P0[k].x + P0[k].y*P0[k].y + P0[k].z*P0[k].z + P0[k].w*P0[k].w
             + P1[k].x*P1[k].x + P1[k].y*P1[k].y + P1[k].z*P1[k].z + P1[k].w*P1[k].w;
    ss = wave_sum(ss);
    if (lane == 0) red[wave*KC + k] = ss;
  }
  __syncthreads();
  if (t < KC){
    float ss = red[t] + red[KC + t] + red[2*KC + t] + red[3*KC + t];
    sInv[t] = 1.0f / fmaxf(sqrtf(ss), 1e-12f);
  }
  __syncthreads();
  float invP[KC];
  #pragma unroll
  for (int k = 0; k < KC; ++k) invP[k] = sInv[k];

  int tok = blockIdx.x;
  float4 nx0 = make_float4(0,0,0,0), nx1 = make_float4(0,0,0,0);
  if (tok < ntok){
    nx0 = *(const float4*)(x + (size_t)tok*DDIM + d0);
    nx1 = *(const float4*)(x + (size_t)tok*DDIM + d1);
  }
  for (; tok < ntok; tok += gridDim.x){
    float4 cx0 = nx0, cx1 = nx1;
    int nt = tok + gridDim.x;
    if (nt < ntok){
      nx0 = *(const float4*)(x + (size_t)nt*DDIM + d0);
      nx1 = *(const float4*)(x + (size_t)nt*DDIM + d1);
    }
    float dot[KC];
    #pragma unroll
    for (int k = 0; k < KC; ++k){
      float dv = cx0.x*P0[k].x + cx0.y*P0[k].y + cx0.z*P0[k].z + cx0.w*P0[k].w
               + cx1.x*P1[k].x + cx1.y*P1[k].y + cx1.z*P1[k].z + cx1.w*P1[k].w;
      dot[k] = wave_sum(dv);
    }
    if (lane == 0){
      #pragma unroll
      for (int k = 0; k < KC; ++k) red[wave*KC + k] = dot[k];
    }
    __syncthreads();
    if (t == 0){
      int best = 0; float bv = -3.4e38f;
      #pragma unroll
      for (int k = 0; k < KC; ++k){
        float v = (red[k] + red[KC+k] + red[2*KC+k] + red[3*KC+k]) * invP[k];
        if (v > bv){ bv = v; best = k; }   // strict > : first index wins ties (matches argmax)
      }
      sA = best;
      sCnt[best] += 1.0f;
    }
    __syncthreads();
    const int a = sA;
    #pragma unroll
    for (int k = 0; k < KC; ++k){
      if (a == k){
        acc0[k].x += cx0.x; acc0[k].y += cx0.y; acc0[k].z += cx0.z; acc0[k].w += cx0.w;
        acc1[k].x += cx1.x; acc1[k].y += cx1.y; acc1[k].z += cx1.z; acc1[k].w += cx1.w;
      }
    }
  }
  __syncthreads();
  float* dst = psums + (size_t)blockIdx.x * (KC*DDIM);
  #pragma unroll
  for (int k = 0; k < KC; ++k){
    *(float4*)(dst + k*DDIM + d0) = acc0[k];
    *(float4*)(dst + k*DDIM + d1) = acc1[k];
  }
  if (t < KC) pcnts[blockIdx.x*KC + t] = sCnt[t];
}

// ---------------------------------------------------------------------------
// Reduce per-block partials -> centroids (with count>0 fallback to proto).
// ---------------------------------------------------------------------------
__global__ void k_reduce(const float* __restrict__ psums, const float* __restrict__ pcnts,
                         const float* __restrict__ proto, float* __restrict__ centroid, int nb)
{
  __shared__ float cnt[KC];
  const int tid = blockIdx.x*256 + threadIdx.x;   // 0..16383 -> (k,d)
  if (threadIdx.x < KC){
    float c = 0.f;
    for (int b = 0; b < nb; ++b) c += pcnts[b*KC + threadIdx.x];
    cnt[threadIdx.x] = c;
  }
  __syncthreads();
  float s = 0.f;
  for (int b = 0; b < nb; ++b) s += psums[(size_t)b*(KC*DDIM) + tid];
  const int k = tid >> 11;
  const float c = cnt[k];
  centroid[tid] = (c > 0.f) ? (s / fmaxf(c, 1.f)) : proto[tid];
}

// ---------------------------------------------------------------------------
// new_P = normalize(centroid, 1e-12); P2 = m*P + (1-m)*new_P;
// P2n = normalize(P2, 1e-8).  One block, wave w handles cluster w.
// ---------------------------------------------------------------------------
__global__ void k_pupdate(const float* __restrict__ centroid, const float* __restrict__ proto,
                          float* __restrict__ p2n)
{
  const int t = threadIdx.x;
  const int w = t >> 6, lane = t & 63;
  float4 c[8], pr[8];
  float ss = 0.f;
  #pragma unroll
  for (int j = 0; j < 8; ++j){
    const int d = (j*64 + lane)*4;
    c[j]  = *(const float4*)(centroid + w*DDIM + d);
    pr[j] = *(const float4*)(proto    + w*DDIM + d);
    ss += c[j].x*c[j].x + c[j].y*c[j].y + c[j].z*c[j].z + c[j].w*c[j].w;
  }
  ss = wave_sum(ss);
  const float invc = 1.0f / fmaxf(sqrtf(ss), 1e-12f);
  const float m = 0.999f, om = 1.0f - 0.999f;
  float4 p2[8];
  float ss2 = 0.f;
  #pragma unroll
  for (int j = 0; j < 8; ++j){
    p2[j].x = m*pr[j].x + om*c[j].x*invc;
    p2[j].y = m*pr[j].y + om*c[j].y*invc;
    p2[j].z = m*pr[j].z + om*c[j].z*invc;
    p2[j].w = m*pr[j].w + om*c[j].w*invc;
    ss2 += p2[j].x*p2[j].x + p2[j].y*p2[j].y + p2[j].z*p2[j].z + p2[j].w*p2[j].w;
  }
  ss2 = wave_sum(ss2);
  const float inv2 = 1.0f / fmaxf(sqrtf(ss2), 1e-8f);
  #pragma unroll
  for (int j = 0; j < 8; ++j){
    const int d = (j*64 + lane)*4;
    float4 o;
    o.x = p2[j].x*inv2; o.y = p2[j].y*inv2; o.z = p2[j].z*inv2; o.w = p2[j].w*inv2;
    *(float4*)(p2n + w*DDIM + d) = o;
  }
}

// ---------------------------------------------------------------------------
// Pass C: sims2 = clip(xn @ P2n^T), novelty -> scale -> gelu(x*scale).
// Same slice structure as k_assign; P2n in 64 VGPRs/thread.
// ---------------------------------------------------------------------------
__global__ __launch_bounds__(256, 2)
void k_final(const float* __restrict__ x, const float* __restrict__ p2n,
             const float* __restrict__ plog_tau, const float* __restrict__ plog_blend,
             float* __restrict__ out, int ntok)
{
  const int t = threadIdx.x;
  const int wave = t >> 6, lane = t & 63;
  const int d0 = 4*t, d1 = DDIM/2 + 4*t;

  __shared__ float red[4*(KC+1)];
  __shared__ float sScale;

  float4 P0[KC], P1[KC];
  #pragma unroll
  for (int k = 0; k < KC; ++k){
    P0[k] = *(const float4*)(p2n + k*DDIM + d0);
    P1[k] = *(const float4*)(p2n + k*DDIM + d1);
  }
  const float tau   = __expf(plog_tau[0]);
  const float alpha = 1.0f / (1.0f + __expf(-plog_blend[0]));

  int tok = blockIdx.x;
  float4 nx0 = make_float4(0,0,0,0), nx1 = make_float4(0,0,0,0);
  if (tok < ntok){
    nx0 = *(const float4*)(x + (size_t)tok*DDIM + d0);
    nx1 = *(const float4*)(x + (size_t)tok*DDIM + d1);
  }
  for (; tok < ntok; tok += gridDim.x){
    float4 cx0 = nx0, cx1 = nx1;
    int nt = tok + gridDim.x;
    if (nt < ntok){
      nx0 = *(const float4*)(x + (size_t)nt*DDIM + d0);
      nx1 = *(const float4*)(x + (size_t)nt*DDIM + d1);
    }
    float ss = cx0.x*cx0.x + cx0.y*cx0.y + cx0.z*cx0.z + cx0.w*cx0.w
             + cx1.x*cx1.x + cx1.y*cx1.y + cx1.z*cx1.z + cx1.w*cx1.w;
    ss = wave_sum(ss);
    float dot[KC];
    #pragma unroll
    for (int k = 0; k < KC; ++k){
      float dv = cx0.x*P0[k].x + cx0.y*P0[k].y + cx0.z*P0[k].z + cx0.w*P0[k].w
               + cx1.x*P1[k].x + cx1.y*P1[k].y + cx1.z*P1[k].z + cx1.w*P1[k].w;
      dot[k] = wave_sum(dv);
    }
    if (lane == 0){
      #pragma unroll
      for (int k = 0; k < KC; ++k) red[wave*(KC+1) + k] = dot[k];
      red[wave*(KC+1) + KC] = ss;
    }
    __syncthreads();
    if (t == 0){
      float fss = red[KC] + red[(KC+1)+KC] + red[2*(KC+1)+KC] + red[3*(KC+1)+KC];
      float inv = 1.0f / fmaxf(sqrtf(fss), 1e-8f);   // xn eps 1e-8
      float mx = -3.4e38f;
      #pragma unroll
      for (int k = 0; k < KC; ++k){
        float v = red[k] + red[(KC+1)+k] + red[2*(KC+1)+k] + red[3*(KC+1)+k];
        mx = fmaxf(mx, v);
      }
      float s    = fminf(fmaxf(mx * inv, -1.0f), 1.0f);   // clip(max) == max(clip)
      float dist = fminf(fmaxf(1.0f - s, 0.0f), 2.0f);
      float nov  = 1.0f - __expf(-tau * dist);
      float sc   = 1.0f - alpha + alpha * nov;
      sScale = fminf(fmaxf(sc, 0.1f), 10.0f);
    }
    __syncthreads();
    const float sc = sScale;
    float* o = out + (size_t)tok*DDIM;
    float4 o0, o1;
    o0.x = gelu_tanh(cx0.x*sc); o0.y = gelu_tanh(cx0.y*sc);
    o0.z = gelu_tanh(cx0.z*sc); o0.w = gelu_tanh(cx0.w*sc);
    o1.x = gelu_tanh(cx1.x*sc); o1.y = gelu_tanh(cx1.y*sc);
    o1.z = gelu_tanh(cx1.z*sc); o1.w = gelu_tanh(cx1.w*sc);
    *(float4*)(o + d0) = o0;
    *(float4*)(o + d1) = o1;
  }
}

extern "C" void kernel_launch(void* const* d_in, const int* in_sizes, int n_in,
                              void* d_out, int out_size, void* d_ws, size_t ws_size,
                              hipStream_t stream)
{
  const float* x          = (const float*)d_in[0];
  const float* proto      = (const float*)d_in[1];
  const float* log_tau    = (const float*)d_in[2];
  const float* log_blend  = (const float*)d_in[3];
  float* out = (float*)d_out;
  float* ws  = (float*)d_ws;

  const int ntok = in_sizes[0] / DDIM;   // 16384

  // ws layout (floats):
  float* centroid = ws;               // 16384
  float* p2n      = ws + 16384;       // 16384
  float* pcnts    = ws + 32768;       // up to 512*8 = 4096
  float* psums    = ws + 36864;       // nb * 16384

  long cap = (long)(ws_size / 4) - 36864;
  int nb = (int)(cap / (KC * DDIM));
  if (nb > 512) nb = 512;
  if (nb < 1)  nb = 1;

  k_assign <<<nb,  256, 0, stream>>>(x, proto, psums, pcnts, ntok);
  k_reduce <<<64,  256, 0, stream>>>(psums, pcnts, proto, centroid, nb);
  k_pupdate<<<1,   512, 0, stream>>>(centroid, proto, p2n);
  k_final  <<<512, 256, 0, stream>>>(x, p2n, log_tau, log_blend, out, ntok);
}

// Round 3
// 353.329 us; speedup vs baseline: 1.3676x; 1.3676x over previous
//
#include <hip/hip_runtime.h>

#define N_TOK 16384
#define DDIM  2048
#define KC    8
#define CH1   32          // stage-1 reduction chunks over nb

typedef float nfloat4 __attribute__((ext_vector_type(4)));   // native vec for nontemporal builtins

__device__ __forceinline__ void nt_store4(const float4& v, float* p){
  nfloat4 nv; nv.x = v.x; nv.y = v.y; nv.z = v.z; nv.w = v.w;
  __builtin_nontemporal_store(nv, (nfloat4*)p);
}
__device__ __forceinline__ float4 nt_load4(const float* p){
  nfloat4 nv = __builtin_nontemporal_load((const nfloat4*)p);
  return make_float4(nv.x, nv.y, nv.z, nv.w);
}

__device__ __forceinline__ float wave_sum(float v){
  #pragma unroll
  for (int off = 32; off > 0; off >>= 1)
    v += __shfl_xor(v, off, 64);
  return v;
}

__device__ __forceinline__ float gelu_tanh(float v){
  const float c = 0.7978845608028654f;
  float tt = c * v * (1.0f + 0.044715f * v * v);
  float e  = __expf(2.0f * tt);
  float th = 1.0f - 2.0f / (e + 1.0f);
  return 0.5f * v * (1.0f + th);
}

// ---------------------------------------------------------------------------
// Pass A: per-token argmax assignment + per-block segment partial sums.
// Block = 256 threads; thread t owns d = {4t..4t+3} and {1024+4t..1024+4t+3}.
// Prototypes (raw) held in 64 VGPRs/thread; segment sums in 64 acc VGPRs.
// ---------------------------------------------------------------------------
__global__ __launch_bounds__(256, 2)
void k_assign(const float* __restrict__ x, const float* __restrict__ proto,
              float* __restrict__ psums, float* __restrict__ pcnts, int ntok)
{
  const int t = threadIdx.x;
  const int wave = t >> 6, lane = t & 63;
  const int d0 = 4*t, d1 = DDIM/2 + 4*t;

  __shared__ float red[4*KC];
  __shared__ float sInv[KC];
  __shared__ float sCnt[KC];
  __shared__ int   sA;

  float4 P0[KC], P1[KC];
  float4 acc0[KC], acc1[KC];
  #pragma unroll
  for (int k = 0; k < KC; ++k){
    P0[k] = *(const float4*)(proto + k*DDIM + d0);
    P1[k] = *(const float4*)(proto + k*DDIM + d1);
    acc0[k] = make_float4(0.f,0.f,0.f,0.f);
    acc1[k] = make_float4(0.f,0.f,0.f,0.f);
  }
  if (t < KC) sCnt[t] = 0.f;

  // 1/||P_k|| (eps 1e-12). argmax of dot*invP == argmax of clipped cosine
  // sims (positive scale + monotone clip preserve argmax).
  #pragma unroll
  for (int k = 0; k < KC; ++k){
    float ss = P0[k].x*P0[k].x + P0[k].y*P0[k].y + P0[k].z*P0[k].z + P0[k].w*P0[k].w
             + P1[k].x*P1[k].x + P1[k].y*P1[k].y + P1[k].z*P1[k].z + P1[k].w*P1[k].w;
    ss = wave_sum(ss);
    if (lane == 0) red[wave*KC + k] = ss;
  }
  __syncthreads();
  if (t < KC){
    float ss = red[t] + red[KC + t] + red[2*KC + t] + red[3*KC + t];
    sInv[t] = 1.0f / fmaxf(sqrtf(ss), 1e-12f);
  }
  __syncthreads();
  float invP[KC];
  #pragma unroll
  for (int k = 0; k < KC; ++k) invP[k] = sInv[k];

  int tok = blockIdx.x;
  float4 nx0 = make_float4(0,0,0,0), nx1 = make_float4(0,0,0,0);
  if (tok < ntok){
    nx0 = *(const float4*)(x + (size_t)tok*DDIM + d0);
    nx1 = *(const float4*)(x + (size_t)tok*DDIM + d1);
  }
  for (; tok < ntok; tok += gridDim.x){
    float4 cx0 = nx0, cx1 = nx1;
    int nt = tok + gridDim.x;
    if (nt < ntok){
      nx0 = *(const float4*)(x + (size_t)nt*DDIM + d0);
      nx1 = *(const float4*)(x + (size_t)nt*DDIM + d1);
    }
    float dot[KC];
    #pragma unroll
    for (int k = 0; k < KC; ++k){
      float dv = cx0.x*P0[k].x + cx0.y*P0[k].y + cx0.z*P0[k].z + cx0.w*P0[k].w
               + cx1.x*P1[k].x + cx1.y*P1[k].y + cx1.z*P1[k].z + cx1.w*P1[k].w;
      dot[k] = wave_sum(dv);
    }
    if (lane == 0){
      #pragma unroll
      for (int k = 0; k < KC; ++k) red[wave*KC + k] = dot[k];
    }
    __syncthreads();
    if (t == 0){
      int best = 0; float bv = -3.4e38f;
      #pragma unroll
      for (int k = 0; k < KC; ++k){
        float v = (red[k] + red[KC+k] + red[2*KC+k] + red[3*KC+k]) * invP[k];
        if (v > bv){ bv = v; best = k; }   // strict > : first index wins ties
      }
      sA = best;
      sCnt[best] += 1.0f;
    }
    __syncthreads();
    const int a = sA;
    #pragma unroll
    for (int k = 0; k < KC; ++k){
      if (a == k){
        acc0[k].x += cx0.x; acc0[k].y += cx0.y; acc0[k].z += cx0.z; acc0[k].w += cx0.w;
        acc1[k].x += cx1.x; acc1[k].y += cx1.y; acc1[k].z += cx1.z; acc1[k].w += cx1.w;
      }
    }
  }
  __syncthreads();
  // nontemporal: write-once, read-once by k_reduce1 — keep x L3-resident
  float* dst = psums + (size_t)blockIdx.x * (KC*DDIM);
  #pragma unroll
  for (int k = 0; k < KC; ++k){
    nt_store4(acc0[k], dst + k*DDIM + d0);
    nt_store4(acc1[k], dst + k*DDIM + d1);
  }
  if (t < KC) pcnts[blockIdx.x*KC + t] = sCnt[t];
}

// ---------------------------------------------------------------------------
// Reduce stage 1: nb partials -> CH1 chunk-partials.
// grid = CH1*16 blocks; blockIdx = ch*16 + g; thread sums `cs` float4s of
// its column (independent loads — full memory-level parallelism).
// ---------------------------------------------------------------------------
__global__ __launch_bounds__(256)
void k_reduce1(const float* __restrict__ psums, const float* __restrict__ pcnts,
               float* __restrict__ stage2, float* __restrict__ cnt2, int nb, int cs)
{
  const int ch = blockIdx.x >> 4;          // 0..CH1-1
  const int g  = blockIdx.x & 15;          // 0..15
  const int col = g*1024 + threadIdx.x*4;  // float column, 4-wide
  const int b0 = ch*cs;

  float4 acc = make_float4(0.f,0.f,0.f,0.f);
  #pragma unroll 4
  for (int i = 0; i < cs; ++i){
    int b = b0 + i;
    if (b < nb){
      float4 v = nt_load4(psums + (size_t)b*(KC*DDIM) + col);
      acc.x += v.x; acc.y += v.y; acc.z += v.z; acc.w += v.w;
    }
  }
  *(float4*)(stage2 + (size_t)ch*(KC*DDIM) + col) = acc;

  if (g == 0 && threadIdx.x < KC){
    float c = 0.f;
    for (int i = 0; i < cs; ++i){
      int b = b0 + i;
      if (b < nb) c += pcnts[b*KC + threadIdx.x];
    }
    cnt2[ch*KC + threadIdx.x] = c;
  }
}

// ---------------------------------------------------------------------------
// Reduce stage 2: CH1 chunk-partials -> centroid (count>0 fallback to proto).
// grid = 16 blocks x 256 threads; thread sums 32 float4s (unrolled).
// ---------------------------------------------------------------------------
__global__ __launch_bounds__(256)
void k_reduce2(const float* __restrict__ stage2, const float* __restrict__ cnt2,
               const float* __restrict__ proto, float* __restrict__ centroid)
{
  __shared__ float cnt[KC];
  if (threadIdx.x < KC){
    float c = 0.f;
    #pragma unroll
    for (int ch = 0; ch < CH1; ++ch) c += cnt2[ch*KC + threadIdx.x];
    cnt[threadIdx.x] = c;
  }
  __syncthreads();
  const int col = blockIdx.x*1024 + threadIdx.x*4;
  float4 s = make_float4(0.f,0.f,0.f,0.f);
  #pragma unroll
  for (int ch = 0; ch < CH1; ++ch){
    float4 v = *(const float4*)(stage2 + (size_t)ch*(KC*DDIM) + col);
    s.x += v.x; s.y += v.y; s.z += v.z; s.w += v.w;
  }
  const int k = col >> 11;                 // col / 2048 (float4 never crosses k)
  const float c = cnt[k];
  float4 o;
  if (c > 0.f){
    float inv = 1.0f / fmaxf(c, 1.f);
    o.x = s.x*inv; o.y = s.y*inv; o.z = s.z*inv; o.w = s.w*inv;
  } else {
    o = *(const float4*)(proto + col);
  }
  *(float4*)(centroid + col) = o;
}

// ---------------------------------------------------------------------------
// new_P = normalize(centroid, 1e-12); P2 = m*P + (1-m)*new_P;
// P2n = normalize(P2, 1e-8).  One block, wave w handles cluster w.
// ---------------------------------------------------------------------------
__global__ void k_pupdate(const float* __restrict__ centroid, const float* __restrict__ proto,
                          float* __restrict__ p2n)
{
  const int t = threadIdx.x;
  const int w = t >> 6, lane = t & 63;
  float4 c[8], pr[8];
  float ss = 0.f;
  #pragma unroll
  for (int j = 0; j < 8; ++j){
    const int d = (j*64 + lane)*4;
    c[j]  = *(const float4*)(centroid + w*DDIM + d);
    pr[j] = *(const float4*)(proto    + w*DDIM + d);
    ss += c[j].x*c[j].x + c[j].y*c[j].y + c[j].z*c[j].z + c[j].w*c[j].w;
  }
  ss = wave_sum(ss);
  const float invc = 1.0f / fmaxf(sqrtf(ss), 1e-12f);
  const float m = 0.999f, om = 1.0f - 0.999f;
  float4 p2[8];
  float ss2 = 0.f;
  #pragma unroll
  for (int j = 0; j < 8; ++j){
    p2[j].x = m*pr[j].x + om*c[j].x*invc;
    p2[j].y = m*pr[j].y + om*c[j].y*invc;
    p2[j].z = m*pr[j].z + om*c[j].z*invc;
    p2[j].w = m*pr[j].w + om*c[j].w*invc;
    ss2 += p2[j].x*p2[j].x + p2[j].y*p2[j].y + p2[j].z*p2[j].z + p2[j].w*p2[j].w;
  }
  ss2 = wave_sum(ss2);
  const float inv2 = 1.0f / fmaxf(sqrtf(ss2), 1e-8f);
  #pragma unroll
  for (int j = 0; j < 8; ++j){
    const int d = (j*64 + lane)*4;
    float4 o;
    o.x = p2[j].x*inv2; o.y = p2[j].y*inv2; o.z = p2[j].z*inv2; o.w = p2[j].w*inv2;
    *(float4*)(p2n + w*DDIM + d) = o;
  }
}

// ---------------------------------------------------------------------------
// Pass C: sims2 = clip(xn @ P2n^T), novelty -> scale -> gelu(x*scale).
// Same slice structure as k_assign; P2n in 64 VGPRs/thread.
// ---------------------------------------------------------------------------
__global__ __launch_bounds__(256, 2)
void k_final(const float* __restrict__ x, const float* __restrict__ p2n,
             const float* __restrict__ plog_tau, const float* __restrict__ plog_blend,
             float* __restrict__ out, int ntok)
{
  const int t = threadIdx.x;
  const int wave = t >> 6, lane = t & 63;
  const int d0 = 4*t, d1 = DDIM/2 + 4*t;

  __shared__ float red[4*(KC+1)];
  __shared__ float sScale;

  float4 P0[KC], P1[KC];
  #pragma unroll
  for (int k = 0; k < KC; ++k){
    P0[k] = *(const float4*)(p2n + k*DDIM + d0);
    P1[k] = *(const float4*)(p2n + k*DDIM + d1);
  }
  const float tau   = __expf(plog_tau[0]);
  const float alpha = 1.0f / (1.0f + __expf(-plog_blend[0]));

  int tok = blockIdx.x;
  float4 nx0 = make_float4(0,0,0,0), nx1 = make_float4(0,0,0,0);
  if (tok < ntok){
    nx0 = *(const float4*)(x + (size_t)tok*DDIM + d0);
    nx1 = *(const float4*)(x + (size_t)tok*DDIM + d1);
  }
  for (; tok < ntok; tok += gridDim.x){
    float4 cx0 = nx0, cx1 = nx1;
    int nt = tok + gridDim.x;
    if (nt < ntok){
      nx0 = *(const float4*)(x + (size_t)nt*DDIM + d0);
      nx1 = *(const float4*)(x + (size_t)nt*DDIM + d1);
    }
    float ss = cx0.x*cx0.x + cx0.y*cx0.y + cx0.z*cx0.z + cx0.w*cx0.w
             + cx1.x*cx1.x + cx1.y*cx1.y + cx1.z*cx1.z + cx1.w*cx1.w;
    ss = wave_sum(ss);
    float dot[KC];
    #pragma unroll
    for (int k = 0; k < KC; ++k){
      float dv = cx0.x*P0[k].x + cx0.y*P0[k].y + cx0.z*P0[k].z + cx0.w*P0[k].w
               + cx1.x*P1[k].x + cx1.y*P1[k].y + cx1.z*P1[k].z + cx1.w*P1[k].w;
      dot[k] = wave_sum(dv);
    }
    if (lane == 0){
      #pragma unroll
      for (int k = 0; k < KC; ++k) red[wave*(KC+1) + k] = dot[k];
      red[wave*(KC+1) + KC] = ss;
    }
    __syncthreads();
    if (t == 0){
      float fss = red[KC] + red[(KC+1)+KC] + red[2*(KC+1)+KC] + red[3*(KC+1)+KC];
      float inv = 1.0f / fmaxf(sqrtf(fss), 1e-8f);   // xn eps 1e-8
      float mx = -3.4e38f;
      #pragma unroll
      for (int k = 0; k < KC; ++k){
        float v = red[k] + red[(KC+1)+k] + red[2*(KC+1)+k] + red[3*(KC+1)+k];
        mx = fmaxf(mx, v);
      }
      float s    = fminf(fmaxf(mx * inv, -1.0f), 1.0f);   // clip(max) == max(clip)
      float dist = fminf(fmaxf(1.0f - s, 0.0f), 2.0f);
      float nov  = 1.0f - __expf(-tau * dist);
      float sc   = 1.0f - alpha + alpha * nov;
      sScale = fminf(fmaxf(sc, 0.1f), 10.0f);
    }
    __syncthreads();
    const float sc = sScale;
    float* o = out + (size_t)tok*DDIM;
    float4 o0, o1;
    o0.x = gelu_tanh(cx0.x*sc); o0.y = gelu_tanh(cx0.y*sc);
    o0.z = gelu_tanh(cx0.z*sc); o0.w = gelu_tanh(cx0.w*sc);
    o1.x = gelu_tanh(cx1.x*sc); o1.y = gelu_tanh(cx1.y*sc);
    o1.z = gelu_tanh(cx1.z*sc); o1.w = gelu_tanh(cx1.w*sc);
    // out is never re-read: nontemporal keeps x L3-resident
    nt_store4(o0, o + d0);
    nt_store4(o1, o + d1);
  }
}

extern "C" void kernel_launch(void* const* d_in, const int* in_sizes, int n_in,
                              void* d_out, int out_size, void* d_ws, size_t ws_size,
                              hipStream_t stream)
{
  const float* x          = (const float*)d_in[0];
  const float* proto      = (const float*)d_in[1];
  const float* log_tau    = (const float*)d_in[2];
  const float* log_blend  = (const float*)d_in[3];
  float* out = (float*)d_out;
  float* ws  = (float*)d_ws;

  const int ntok = in_sizes[0] / DDIM;   // 16384

  // ws layout (floats):
  float* centroid = ws;                        // 16384
  float* p2n      = ws + 16384;                // 16384
  float* pcnts    = ws + 32768;                // up to 512*8 = 4096
  float* cnt2     = ws + 36864;                // CH1*8 = 256
  float* stage2   = ws + 37120;                // CH1*16384 = 524288
  float* psums    = ws + 37120 + CH1*KC*DDIM;  // nb * 16384

  long cap = (long)(ws_size / 4) - (37120 + CH1*KC*DDIM);
  int nb = (int)(cap / (KC * DDIM));
  if (nb > 512) nb = 512;
  if (nb < 1)  nb = 1;
  const int cs = (nb + CH1 - 1) / CH1;         // partials per stage-1 chunk

  k_assign <<<nb,      256, 0, stream>>>(x, proto, psums, pcnts, ntok);
  k_reduce1<<<CH1*16,  256, 0, stream>>>(psums, pcnts, stage2, cnt2, nb, cs);
  k_reduce2<<<16,      256, 0, stream>>>(stage2, cnt2, proto, centroid);
  k_pupdate<<<1,       512, 0, stream>>>(centroid, proto, p2n);
  k_final  <<<512,     256, 0, stream>>>(x, p2n, log_tau, log_blend, out, ntok);
}

// Round 4
// 306.777 us; speedup vs baseline: 1.5752x; 1.1517x over previous
//
#include <hip/hip_runtime.h>

#define N_TOK 16384
#define DDIM  2048
#define KC    8
#define CH1   32          // stage-1 reduction chunks over nb
#define TBA   4           // tokens per batch, k_assign
#define TBF   4           // tokens per batch, k_final

typedef float nfloat4 __attribute__((ext_vector_type(4)));   // native vec for nontemporal builtins

__device__ __forceinline__ void nt_store4(const float4& v, float* p){
  nfloat4 nv; nv.x = v.x; nv.y = v.y; nv.z = v.z; nv.w = v.w;
  __builtin_nontemporal_store(nv, (nfloat4*)p);
}
__device__ __forceinline__ float4 nt_load4(const float* p){
  nfloat4 nv = __builtin_nontemporal_load((const nfloat4*)p);
  return make_float4(nv.x, nv.y, nv.z, nv.w);
}

__device__ __forceinline__ float wave_sum(float v){
  #pragma unroll
  for (int off = 32; off > 0; off >>= 1)
    v += __shfl_xor(v, off, 64);
  return v;
}

// Multi-value butterfly: sum v[0..7] across 64 lanes in 10 shuffles.
// On exit, lane l (l<8) holds the full wave-sum for k = 4*(l&1)+2*((l>>1)&1)+((l>>2)&1).
__device__ __forceinline__ float butterfly8(float v[8], int t){
  { // xor 1: keep k-range j+4*(t&1), send the other half
    const bool h = (t & 1);
    #pragma unroll
    for (int j = 0; j < 4; ++j){
      float s    = h ? v[j]   : v[j+4];
      float keep = h ? v[j+4] : v[j];
      v[j] = keep + __shfl_xor(s, 1, 64);
    }
  }
  { // xor 2
    const bool h = (t & 2);
    #pragma unroll
    for (int j = 0; j < 2; ++j){
      float s    = h ? v[j]   : v[j+2];
      float keep = h ? v[j+2] : v[j];
      v[j] = keep + __shfl_xor(s, 2, 64);
    }
  }
  { // xor 4
    const bool h = (t & 4);
    float s    = h ? v[0] : v[1];
    float keep = h ? v[1] : v[0];
    v[0] = keep + __shfl_xor(s, 4, 64);
  }
  v[0] += __shfl_xor(v[0], 8, 64);
  v[0] += __shfl_xor(v[0], 16, 64);
  v[0] += __shfl_xor(v[0], 32, 64);
  return v[0];
}

__device__ __forceinline__ float gelu_tanh(float v){
  const float c = 0.7978845608028654f;
  float tt = c * v * (1.0f + 0.044715f * v * v);
  float e  = __expf(2.0f * tt);
  float th = 1.0f - 2.0f / (e + 1.0f);
  return 0.5f * v * (1.0f + th);
}

// ---------------------------------------------------------------------------
// Pass A: per-token argmax assignment + per-block segment partial sums.
// Batched TB tokens/iter: butterfly8 reduction (10 shuffles vs 48), 2 barriers
// per batch, parallel per-token argmax, register prefetch of next batch.
// ---------------------------------------------------------------------------
__global__ __launch_bounds__(256, 2)
void k_assign(const float* __restrict__ x, const float* __restrict__ proto,
              float* __restrict__ psums, float* __restrict__ pcnts, int ntok)
{
  const int t = threadIdx.x;
  const int wave = t >> 6, lane = t & 63;
  const int d0 = 4*t, d1 = DDIM/2 + 4*t;
  const int kidx = ((lane&1)<<2) | (lane&2) | ((lane>>2)&1);   // butterfly8 output k

  __shared__ float rednorm[4*KC];
  __shared__ float red[TBA][4][KC];
  __shared__ float sInv[KC];
  __shared__ float sCnt[KC];
  __shared__ int   sAsg[TBA];

  float4 P0[KC], P1[KC];
  float4 acc0[KC], acc1[KC];
  #pragma unroll
  for (int k = 0; k < KC; ++k){
    P0[k] = *(const float4*)(proto + k*DDIM + d0);
    P1[k] = *(const float4*)(proto + k*DDIM + d1);
    acc0[k] = make_float4(0.f,0.f,0.f,0.f);
    acc1[k] = make_float4(0.f,0.f,0.f,0.f);
  }
  if (t < KC) sCnt[t] = 0.f;

  // 1/||P_k|| (eps 1e-12). argmax of dot*invP == argmax of clipped cosine.
  #pragma unroll
  for (int k = 0; k < KC; ++k){
    float ss = P0[k].x*P0[k].x + P0[k].y*P0[k].y + P0[k].z*P0[k].z + P0[k].w*P0[k].w
             + P1[k].x*P1[k].x + P1[k].y*P1[k].y + P1[k].z*P1[k].z + P1[k].w*P1[k].w;
    ss = wave_sum(ss);
    if (lane == 0) rednorm[wave*KC + k] = ss;
  }
  __syncthreads();
  if (t < KC){
    float ss = rednorm[t] + rednorm[KC + t] + rednorm[2*KC + t] + rednorm[3*KC + t];
    sInv[t] = 1.0f / fmaxf(sqrtf(ss), 1e-12f);
  }
  __syncthreads();

  const int stride = gridDim.x * TBA;
  float4 X0[TBA], X1[TBA], N0[TBA], N1[TBA];
  int tok0 = blockIdx.x * TBA;
  #pragma unroll
  for (int i = 0; i < TBA; ++i){
    int tk = tok0 + i;
    X0[i] = make_float4(0,0,0,0); X1[i] = make_float4(0,0,0,0);
    if (tk < ntok){
      X0[i] = *(const float4*)(x + (size_t)tk*DDIM + d0);
      X1[i] = *(const float4*)(x + (size_t)tk*DDIM + d1);
    }
  }

  for (; tok0 < ntok; tok0 += stride){
    const int ntok0 = tok0 + stride;
    #pragma unroll
    for (int i = 0; i < TBA; ++i){
      int tk = ntok0 + i;
      N0[i] = make_float4(0,0,0,0); N1[i] = make_float4(0,0,0,0);
      if (tk < ntok){
        N0[i] = *(const float4*)(x + (size_t)tk*DDIM + d0);
        N1[i] = *(const float4*)(x + (size_t)tk*DDIM + d1);
      }
    }
    // dot partials + butterfly reduce, one LDS write per wave per token
    #pragma unroll
    for (int i = 0; i < TBA; ++i){
      float v[KC];
      #pragma unroll
      for (int k = 0; k < KC; ++k){
        v[k] = X0[i].x*P0[k].x + X0[i].y*P0[k].y + X0[i].z*P0[k].z + X0[i].w*P0[k].w
             + X1[i].x*P1[k].x + X1[i].y*P1[k].y + X1[i].z*P1[k].z + X1[i].w*P1[k].w;
      }
      float r = butterfly8(v, t);
      if (lane < 8) red[i][wave][kidx] = r;
    }
    __syncthreads();
    if (t < TBA && tok0 + t < ntok){
      int best = 0; float bv = -3.4e38f;
      #pragma unroll
      for (int k = 0; k < KC; ++k){
        float val = (red[t][0][k] + red[t][1][k] + red[t][2][k] + red[t][3][k]) * sInv[k];
        if (val > bv){ bv = val; best = k; }   // strict > : first index wins ties
      }
      sAsg[t] = best;
      atomicAdd(&sCnt[best], 1.0f);
    }
    __syncthreads();
    #pragma unroll
    for (int i = 0; i < TBA; ++i){
      if (tok0 + i < ntok){
        const int a = sAsg[i];   // block-uniform -> scalar branch
        #pragma unroll
        for (int k = 0; k < KC; ++k){
          if (a == k){
            acc0[k].x += X0[i].x; acc0[k].y += X0[i].y; acc0[k].z += X0[i].z; acc0[k].w += X0[i].w;
            acc1[k].x += X1[i].x; acc1[k].y += X1[i].y; acc1[k].z += X1[i].z; acc1[k].w += X1[i].w;
          }
        }
      }
    }
    #pragma unroll
    for (int i = 0; i < TBA; ++i){ X0[i] = N0[i]; X1[i] = N1[i]; }
  }
  __syncthreads();
  // nontemporal: write-once, read-once by k_reduce1 — keep x L3-resident
  float* dst = psums + (size_t)blockIdx.x * (KC*DDIM);
  #pragma unroll
  for (int k = 0; k < KC; ++k){
    nt_store4(acc0[k], dst + k*DDIM + d0);
    nt_store4(acc1[k], dst + k*DDIM + d1);
  }
  if (t < KC) pcnts[blockIdx.x*KC + t] = sCnt[t];
}

// ---------------------------------------------------------------------------
// Reduce stage 1: nb partials -> CH1 chunk-partials.
// ---------------------------------------------------------------------------
__global__ __launch_bounds__(256)
void k_reduce1(const float* __restrict__ psums, const float* __restrict__ pcnts,
               float* __restrict__ stage2, float* __restrict__ cnt2, int nb, int cs)
{
  const int ch = blockIdx.x >> 4;          // 0..CH1-1
  const int g  = blockIdx.x & 15;          // 0..15
  const int col = g*1024 + threadIdx.x*4;  // float column, 4-wide
  const int b0 = ch*cs;

  float4 acc = make_float4(0.f,0.f,0.f,0.f);
  #pragma unroll 4
  for (int i = 0; i < cs; ++i){
    int b = b0 + i;
    if (b < nb){
      float4 v = nt_load4(psums + (size_t)b*(KC*DDIM) + col);
      acc.x += v.x; acc.y += v.y; acc.z += v.z; acc.w += v.w;
    }
  }
  *(float4*)(stage2 + (size_t)ch*(KC*DDIM) + col) = acc;

  if (g == 0 && threadIdx.x < KC){
    float c = 0.f;
    for (int i = 0; i < cs; ++i){
      int b = b0 + i;
      if (b < nb) c += pcnts[b*KC + threadIdx.x];
    }
    cnt2[ch*KC + threadIdx.x] = c;
  }
}

// ---------------------------------------------------------------------------
// Reduce stage 2: CH1 chunk-partials -> centroid (count>0 fallback to proto).
// ---------------------------------------------------------------------------
__global__ __launch_bounds__(256)
void k_reduce2(const float* __restrict__ stage2, const float* __restrict__ cnt2,
               const float* __restrict__ proto, float* __restrict__ centroid)
{
  __shared__ float cnt[KC];
  if (threadIdx.x < KC){
    float c = 0.f;
    #pragma unroll
    for (int ch = 0; ch < CH1; ++ch) c += cnt2[ch*KC + threadIdx.x];
    cnt[threadIdx.x] = c;
  }
  __syncthreads();
  const int col = blockIdx.x*1024 + threadIdx.x*4;
  float4 s = make_float4(0.f,0.f,0.f,0.f);
  #pragma unroll
  for (int ch = 0; ch < CH1; ++ch){
    float4 v = *(const float4*)(stage2 + (size_t)ch*(KC*DDIM) + col);
    s.x += v.x; s.y += v.y; s.z += v.z; s.w += v.w;
  }
  const int k = col >> 11;
  const float c = cnt[k];
  float4 o;
  if (c > 0.f){
    float inv = 1.0f / fmaxf(c, 1.f);
    o.x = s.x*inv; o.y = s.y*inv; o.z = s.z*inv; o.w = s.w*inv;
  } else {
    o = *(const float4*)(proto + col);
  }
  *(float4*)(centroid + col) = o;
}

// ---------------------------------------------------------------------------
// new_P = normalize(centroid, 1e-12); P2 = m*P + (1-m)*new_P;
// P2n = normalize(P2, 1e-8).  One block, wave w handles cluster w.
// ---------------------------------------------------------------------------
__global__ void k_pupdate(const float* __restrict__ centroid, const float* __restrict__ proto,
                          float* __restrict__ p2n)
{
  const int t = threadIdx.x;
  const int w = t >> 6, lane = t & 63;
  float4 c[8], pr[8];
  float ss = 0.f;
  #pragma unroll
  for (int j = 0; j < 8; ++j){
    const int d = (j*64 + lane)*4;
    c[j]  = *(const float4*)(centroid + w*DDIM + d);
    pr[j] = *(const float4*)(proto    + w*DDIM + d);
    ss += c[j].x*c[j].x + c[j].y*c[j].y + c[j].z*c[j].z + c[j].w*c[j].w;
  }
  ss = wave_sum(ss);
  const float invc = 1.0f / fmaxf(sqrtf(ss), 1e-12f);
  const float m = 0.999f, om = 1.0f - 0.999f;
  float4 p2[8];
  float ss2 = 0.f;
  #pragma unroll
  for (int j = 0; j < 8; ++j){
    p2[j].x = m*pr[j].x + om*c[j].x*invc;
    p2[j].y = m*pr[j].y + om*c[j].y*invc;
    p2[j].z = m*pr[j].z + om*c[j].z*invc;
    p2[j].w = m*pr[j].w + om*c[j].w*invc;
    ss2 += p2[j].x*p2[j].x + p2[j].y*p2[j].y + p2[j].z*p2[j].z + p2[j].w*p2[j].w;
  }
  ss2 = wave_sum(ss2);
  const float inv2 = 1.0f / fmaxf(sqrtf(ss2), 1e-8f);
  #pragma unroll
  for (int j = 0; j < 8; ++j){
    const int d = (j*64 + lane)*4;
    float4 o;
    o.x = p2[j].x*inv2; o.y = p2[j].y*inv2; o.z = p2[j].z*inv2; o.w = p2[j].w*inv2;
    *(float4*)(p2n + w*DDIM + d) = o;
  }
}

// ---------------------------------------------------------------------------
// Pass C: sims2 -> novelty -> scale -> gelu(x*scale). Batched like k_assign.
// ---------------------------------------------------------------------------
__global__ __launch_bounds__(256, 2)
void k_final(const float* __restrict__ x, const float* __restrict__ p2n,
             const float* __restrict__ plog_tau, const float* __restrict__ plog_blend,
             float* __restrict__ out, int ntok)
{
  const int t = threadIdx.x;
  const int wave = t >> 6, lane = t & 63;
  const int d0 = 4*t, d1 = DDIM/2 + 4*t;
  const int kidx = ((lane&1)<<2) | (lane&2) | ((lane>>2)&1);

  __shared__ float red[TBF][4][KC];
  __shared__ float redss[TBF][4];
  __shared__ float sScale[TBF];

  float4 P0[KC], P1[KC];
  #pragma unroll
  for (int k = 0; k < KC; ++k){
    P0[k] = *(const float4*)(p2n + k*DDIM + d0);
    P1[k] = *(const float4*)(p2n + k*DDIM + d1);
  }
  const float tau   = __expf(plog_tau[0]);
  const float alpha = 1.0f / (1.0f + __expf(-plog_blend[0]));

  const int stride = gridDim.x * TBF;
  float4 X0[TBF], X1[TBF], N0[TBF], N1[TBF];
  int tok0 = blockIdx.x * TBF;
  #pragma unroll
  for (int i = 0; i < TBF; ++i){
    int tk = tok0 + i;
    X0[i] = make_float4(0,0,0,0); X1[i] = make_float4(0,0,0,0);
    if (tk < ntok){
      X0[i] = *(const float4*)(x + (size_t)tk*DDIM + d0);
      X1[i] = *(const float4*)(x + (size_t)tk*DDIM + d1);
    }
  }

  for (; tok0 < ntok; tok0 += stride){
    const int ntok0 = tok0 + stride;
    #pragma unroll
    for (int i = 0; i < TBF; ++i){
      int tk = ntok0 + i;
      N0[i] = make_float4(0,0,0,0); N1[i] = make_float4(0,0,0,0);
      if (tk < ntok){
        N0[i] = *(const float4*)(x + (size_t)tk*DDIM + d0);
        N1[i] = *(const float4*)(x + (size_t)tk*DDIM + d1);
      }
    }
    #pragma unroll
    for (int i = 0; i < TBF; ++i){
      float v[KC];
      #pragma unroll
      for (int k = 0; k < KC; ++k){
        v[k] = X0[i].x*P0[k].x + X0[i].y*P0[k].y + X0[i].z*P0[k].z + X0[i].w*P0[k].w
             + X1[i].x*P1[k].x + X1[i].y*P1[k].y + X1[i].z*P1[k].z + X1[i].w*P1[k].w;
      }
      float r = butterfly8(v, t);
      if (lane < 8) red[i][wave][kidx] = r;
      float ss = X0[i].x*X0[i].x + X0[i].y*X0[i].y + X0[i].z*X0[i].z + X0[i].w*X0[i].w
               + X1[i].x*X1[i].x + X1[i].y*X1[i].y + X1[i].z*X1[i].z + X1[i].w*X1[i].w;
      ss = wave_sum(ss);
      if (lane == 0) redss[i][wave] = ss;
    }
    __syncthreads();
    if (t < TBF && tok0 + t < ntok){
      float fss = redss[t][0] + redss[t][1] + redss[t][2] + redss[t][3];
      float inv = 1.0f / fmaxf(sqrtf(fss), 1e-8f);   // xn eps 1e-8
      float mx = -3.4e38f;
      #pragma unroll
      for (int k = 0; k < KC; ++k){
        float val = red[t][0][k] + red[t][1][k] + red[t][2][k] + red[t][3][k];
        mx = fmaxf(mx, val);
      }
      float s    = fminf(fmaxf(mx * inv, -1.0f), 1.0f);   // clip(max) == max(clip)
      float dist = fminf(fmaxf(1.0f - s, 0.0f), 2.0f);
      float nov  = 1.0f - __expf(-tau * dist);
      float sc   = 1.0f - alpha + alpha * nov;
      sScale[t]  = fminf(fmaxf(sc, 0.1f), 10.0f);
    }
    __syncthreads();
    #pragma unroll
    for (int i = 0; i < TBF; ++i){
      int tk = tok0 + i;
      if (tk < ntok){
        const float sc = sScale[i];
        float* o = out + (size_t)tk*DDIM;
        float4 o0, o1;
        o0.x = gelu_tanh(X0[i].x*sc); o0.y = gelu_tanh(X0[i].y*sc);
        o0.z = gelu_tanh(X0[i].z*sc); o0.w = gelu_tanh(X0[i].w*sc);
        o1.x = gelu_tanh(X1[i].x*sc); o1.y = gelu_tanh(X1[i].y*sc);
        o1.z = gelu_tanh(X1[i].z*sc); o1.w = gelu_tanh(X1[i].w*sc);
        nt_store4(o0, o + d0);
        nt_store4(o1, o + d1);
      }
    }
    #pragma unroll
    for (int i = 0; i < TBF; ++i){ X0[i] = N0[i]; X1[i] = N1[i]; }
  }
}

extern "C" void kernel_launch(void* const* d_in, const int* in_sizes, int n_in,
                              void* d_out, int out_size, void* d_ws, size_t ws_size,
                              hipStream_t stream)
{
  const float* x          = (const float*)d_in[0];
  const float* proto      = (const float*)d_in[1];
  const float* log_tau    = (const float*)d_in[2];
  const float* log_blend  = (const float*)d_in[3];
  float* out = (float*)d_out;
  float* ws  = (float*)d_ws;

  const int ntok = in_sizes[0] / DDIM;   // 16384

  // ws layout (floats):
  float* centroid = ws;                        // 16384
  float* p2n      = ws + 16384;                // 16384
  float* pcnts    = ws + 32768;                // up to 512*8 = 4096
  float* cnt2     = ws + 36864;                // CH1*8 = 256
  float* stage2   = ws + 37120;                // CH1*16384 = 524288
  float* psums    = ws + 37120 + CH1*KC*DDIM;  // nb * 16384

  long cap = (long)(ws_size / 4) - (37120 + CH1*KC*DDIM);
  int nb = (int)(cap / (KC * DDIM));
  if (nb > 512) nb = 512;
  if (nb < 1)  nb = 1;
  const int cs = (nb + CH1 - 1) / CH1;         // partials per stage-1 chunk

  k_assign <<<nb,      256, 0, stream>>>(x, proto, psums, pcnts, ntok);
  k_reduce1<<<CH1*16,  256, 0, stream>>>(psums, pcnts, stage2, cnt2, nb, cs);
  k_reduce2<<<16,      256, 0, stream>>>(stage2, cnt2, proto, centroid);
  k_pupdate<<<1,       512, 0, stream>>>(centroid, proto, p2n);
  k_final  <<<512,     256, 0, stream>>>(x, p2n, log_tau, log_blend, out, ntok);
}